// Round 4
// baseline (121.018 us; speedup 1.0000x reference)
//
#include <hip/hip_runtime.h>
#include <hip/hip_bf16.h>

#define N_ROWS 4096
#define D_DIM  768
#define MARGIN 1.0f
#define EPS_F  1e-12f
#define BK 64            // K-chunk per LDS stage (64 bf16 = 128 B per row)

typedef __bf16 bf16x8 __attribute__((ext_vector_type(8)));
typedef float  f32x4  __attribute__((ext_vector_type(4)));

// async global->LDS DMA, 16 B per lane; LDS dst = wave-uniform base + lane*16
#define GLD16(gp, lp)                                                          \
    __builtin_amdgcn_global_load_lds(                                         \
        (const __attribute__((address_space(1))) void*)(gp),                  \
        (__attribute__((address_space(3))) void*)(lp), 16, 0, 0)

// ---------------------------------------------------------------------------
// Kernel 1: per-row sum of squares (fp32) + bf16 cast, one wave per row.
// ---------------------------------------------------------------------------
__global__ __launch_bounds__(256) void prep_kernel(const float* __restrict__ emb,
                                                   unsigned short* __restrict__ ebf,
                                                   float* __restrict__ sq) {
    const int wave = threadIdx.x >> 6;
    const int lane = threadIdx.x & 63;
    const int row  = blockIdx.x * 4 + wave;

    const float4* rp = (const float4*)(emb + (size_t)row * D_DIM);   // 192 float4/row
    unsigned short* op = ebf + (size_t)row * D_DIM;

    float s = 0.f;
#pragma unroll
    for (int t = 0; t < 3; ++t) {
        const int idx = lane + t * 64;
        float4 v = rp[idx];
        s += v.x * v.x + v.y * v.y + v.z * v.z + v.w * v.w;
        union { ushort4 u4; __hip_bfloat16 h[4]; } o;
        o.h[0] = __float2bfloat16(v.x);
        o.h[1] = __float2bfloat16(v.y);
        o.h[2] = __float2bfloat16(v.z);
        o.h[3] = __float2bfloat16(v.w);
        *(ushort4*)(op + idx * 4) = o.u4;
    }
    for (int off = 32; off; off >>= 1) s += __shfl_down(s, off, 64);
    if (lane == 0) sq[row] = s;
}

// ---------------------------------------------------------------------------
// Kernel 2: 64x64 pair-tile, ONE wave per block (64 threads), 2080 blocks.
// GLD16 staging, XOR-swizzled unpadded LDS (row stride 64 elems = 128 B):
// LDS granule s of row r holds global granule s^(r&7); frag reads use
// granule (4kt+qd)^(ln16&7) -> conflict-free.
// Block order: 4x4 supertiles so ~16 consecutive blocks share 8 row-panels
// (~0.8 MB, fits one XCD's 4 MB L2). Diagonal tiles reuse lA for B.
// Off-diagonal tiles weighted x2; diagonal skips i==j. Scale 1/(N*(N-1)).
// ---------------------------------------------------------------------------
__global__ __launch_bounds__(64) void pair_kernel(const __hip_bfloat16* __restrict__ ebf_,
                                                  const float* __restrict__ sq,
                                                  const int* __restrict__ labels,
                                                  float* __restrict__ out) {
    // ---- supertile block decode ----
    // T = 64 tile rows, 16 super-rows of 4. Diagonal STs: 16 x 10 tiles = 160.
    // Off-diagonal STs (sj > si): 120 x 16 tiles = 1920. Total 2080.
    int ti, tj;
    {
        int b = blockIdx.x;
        if (b < 160) {
            const int s = b / 10;
            int rr = b % 10, di = 0;
            while (rr >= 4 - di) { rr -= 4 - di; ++di; }
            ti = s * 4 + di;
            tj = s * 4 + di + rr;
        } else {
            const int b2 = b - 160;
            int rr = b2 >> 4, si = 0;
            const int w = b2 & 15;
            while (rr >= 15 - si) { rr -= 15 - si; ++si; }
            ti = si * 4 + (w >> 2);
            tj = (si + 1 + rr) * 4 + (w & 3);
        }
    }
    const int i0 = ti * 64, j0 = tj * 64;
    const bool diag = (ti == tj);

    __shared__ __align__(16) unsigned short lA[64 * BK];   // 8 KiB
    __shared__ __align__(16) unsigned short lB[64 * BK];   // 8 KiB

    const unsigned short* ebf = (const unsigned short*)ebf_;
    const int lane = threadIdx.x & 63;
    const int qd   = lane >> 4;
    const int ln16 = lane & 15;

    f32x4 acc[4][4];
#pragma unroll
    for (int m = 0; m < 4; ++m)
#pragma unroll
        for (int n = 0; n < 4; ++n) acc[m][n] = (f32x4){0.f, 0.f, 0.f, 0.f};

    // staging source map: lane l -> row (+l>>3), LDS granule l&7 holding
    // global granule (l&7)^(l>>3)
    const int gr = lane >> 3;
    const int gg = (lane & 7) ^ gr;
    const unsigned short* gA = ebf + (size_t)(i0 + gr) * D_DIM + gg * 8;
    const unsigned short* gB = ebf + (size_t)(j0 + gr) * D_DIM + gg * 8;
    const unsigned short* lBr = diag ? lA : lB;

    for (int k0 = 0; k0 < D_DIM; k0 += BK) {
        __syncthreads();   // single-wave: prior ds_reads done before overwrite
#pragma unroll
        for (int inst = 0; inst < 8; ++inst)
            GLD16(gA + (size_t)inst * 8 * D_DIM + k0, lA + inst * 8 * BK);
        if (!diag) {
#pragma unroll
            for (int inst = 0; inst < 8; ++inst)
                GLD16(gB + (size_t)inst * 8 * D_DIM + k0, lB + inst * 8 * BK);
        }
        __syncthreads();   // vmcnt(0): tiles ready

#pragma unroll
        for (int kt = 0; kt < 2; ++kt) {
            const int sg = ((kt << 2) + qd) ^ (ln16 & 7);   // swizzled granule
            bf16x8 af[4], bv[4];
#pragma unroll
            for (int m = 0; m < 4; ++m)
                af[m] = *(const bf16x8*)&lA[(m * 16 + ln16) * BK + sg * 8];
#pragma unroll
            for (int n = 0; n < 4; ++n)
                bv[n] = *(const bf16x8*)&lBr[(n * 16 + ln16) * BK + sg * 8];
#pragma unroll
            for (int m = 0; m < 4; ++m)
#pragma unroll
                for (int n = 0; n < 4; ++n)
                    acc[m][n] = __builtin_amdgcn_mfma_f32_16x16x32_bf16(
                        af[m], bv[n], acc[m][n], 0, 0, 0);
        }
    }

    // ---- epilogue: contrastive loss per pair ----
    float psum = 0.f;
#pragma unroll
    for (int m = 0; m < 4; ++m) {
#pragma unroll
        for (int n = 0; n < 4; ++n) {
#pragma unroll
            for (int r = 0; r < 4; ++r) {
                const int gi = i0 + m * 16 + qd * 4 + r;   // C row
                const int gj = j0 + n * 16 + ln16;         // C col
                const float g = acc[m][n][r];
                float d2 = fmaxf(sq[gi] + sq[gj] - 2.0f * g, 0.0f);
                const float dist = sqrtf(d2 + EPS_F);
                const float h = fmaxf(MARGIN - dist, 0.0f);
                const float pl = (labels[gi] == labels[gj]) ? d2 : h * h;
                if (gi != gj) psum += pl;
            }
        }
    }

    for (int off = 32; off; off >>= 1) psum += __shfl_down(psum, off, 64);
    if (lane == 0) {
        const float wgt = diag ? 1.0f : 2.0f;
        const float scale = 1.0f / ((float)N_ROWS * (float)(N_ROWS - 1));
        atomicAdd(out, psum * wgt * scale);
    }
}

// ---------------------------------------------------------------------------
extern "C" void kernel_launch(void* const* d_in, const int* in_sizes, int n_in,
                              void* d_out, int out_size, void* d_ws, size_t ws_size,
                              hipStream_t stream) {
    const float* emb  = (const float*)d_in[0];
    const int* labels = (const int*)d_in[1];
    float* out        = (float*)d_out;

    unsigned short* ebf = (unsigned short*)d_ws;
    float* sq = (float*)((char*)d_ws + (size_t)N_ROWS * D_DIM * sizeof(unsigned short));

    hipMemsetAsync(d_out, 0, sizeof(float), stream);
    prep_kernel<<<N_ROWS / 4, 256, 0, stream>>>(emb, ebf, sq);

    pair_kernel<<<2080, 64, 0, stream>>>((const __hip_bfloat16*)ebf, sq, labels, out);
}